// Round 1
// baseline (330.259 us; speedup 1.0000x reference)
//
#include <hip/hip_runtime.h>
#include <stdint.h>

#define SX 2048
#define SYY 2048
#define DDIM 1024
#define NBATCH 8

typedef _Float16 f16;
typedef __attribute__((ext_vector_type(4))) _Float16 h4_t;
typedef __attribute__((ext_vector_type(8))) _Float16 h8_t;
typedef __attribute__((ext_vector_type(4))) float fx4_t;

__device__ __forceinline__ void gload_lds16(const void* g, void* l) {
  __builtin_amdgcn_global_load_lds((const __attribute__((address_space(1))) void*)g,
                                   (__attribute__((address_space(3))) void*)l,
                                   16, 0, 0);
}

// ---- copy x into out[:, :, 0:D] (fp32) ----
__global__ __launch_bounds__(256) void k_copy_x(const float4* __restrict__ x,
                                                float* __restrict__ out, long n4) {
  long i = (long)blockIdx.x * blockDim.x + threadIdx.x;
  long stride = (long)gridDim.x * blockDim.x;
  for (; i < n4; i += stride) {
    long bi = i >> 8;            // / (DDIM/4)
    int dq = (int)(i & 255);
    float4 v = x[i];
    *(float4*)(out + bi * (2 * DDIM) + dq * 4) = v;
  }
}

// ---- fp32 -> fp16 row-major convert ----
__global__ __launch_bounds__(256) void k_cvt16(const float4* __restrict__ src,
                                               h4_t* __restrict__ dst, long n4) {
  long i = (long)blockIdx.x * blockDim.x + threadIdx.x;
  long stride = (long)gridDim.x * blockDim.x;
  for (; i < n4; i += stride) {
    float4 v = src[i];
    h4_t h = { (f16)v.x, (f16)v.y, (f16)v.z, (f16)v.w };
    dst[i] = h;
  }
}

// ---- y[z][j][d] fp32 -> Y16[z][j][d] fp16 and Yt16[z][d][j] fp16 ----
__global__ __launch_bounds__(256) void k_trans(const float* __restrict__ y,
                                               f16* __restrict__ y16,
                                               f16* __restrict__ yt16) {
  __shared__ f16 tile[64][72];
  int z = blockIdx.z;
  int d0 = blockIdx.x * 64, j0 = blockIdx.y * 64;
  const float* yb = y + (size_t)z * SYY * DDIM;
  f16* y16b = y16 + (size_t)z * SYY * DDIM;
  f16* ytb = yt16 + (size_t)z * DDIM * SYY;
  int t = threadIdx.x;
  int jl = t >> 2;     // 0..63 (row within tile)
  int dq = t & 3;      // covers 16 d each
#pragma unroll
  for (int s = 0; s < 4; ++s) {
    int dl = dq * 16 + s * 4;
    float4 v = *(const float4*)(yb + (size_t)(j0 + jl) * DDIM + d0 + dl);
    h4_t h = { (f16)v.x, (f16)v.y, (f16)v.z, (f16)v.w };
    *(h4_t*)(y16b + (size_t)(j0 + jl) * DDIM + d0 + dl) = h;
    *(h4_t*)&tile[jl][dl] = h;
  }
  __syncthreads();
  int dl2 = t >> 2;    // 0..63 local d
  int jq = t & 3;      // 16 j each
  f16 vbuf[16] __attribute__((aligned(16)));
#pragma unroll
  for (int u = 0; u < 16; ++u) vbuf[u] = tile[jq * 16 + u][dl2];
  f16* orow = ytb + (size_t)(d0 + dl2) * SYY + j0 + jq * 16;
  *(uint4*)orow = *(const uint4*)&vbuf[0];
  *(uint4*)(orow + 8) = *(const uint4*)&vbuf[8];
}

// ---- generic f16 GEMM: C[m][n] (+=0) = sum_k A[m][k]*B[n][k]  (both K-major) ----
// 128x128 tile, BK=64, 4 waves, 16x16x32 f16 MFMA, global_load_lds + XOR swizzle.
__global__ __launch_bounds__(256) void k_gemm(
    const f16* __restrict__ A, long a_zs, int a_row0, int lda,
    const f16* __restrict__ B, long b_zs, int ldb,
    float* __restrict__ C, long c_zs, int c_row0, int ldc, int c_col0,
    int K)
{
  __shared__ f16 As[128 * 64];
  __shared__ f16 Bs[128 * 64];
  const int tid = threadIdx.x;
  const int lane = tid & 63;
  const int wv = tid >> 6;
  const int wr = wv >> 1, wc = wv & 1;
  const int z = blockIdx.z;
  const int n0 = blockIdx.x * 128;
  const int m0 = blockIdx.y * 128;

  const f16* Ab = A + (size_t)z * a_zs + (size_t)(a_row0 + m0) * lda;
  const f16* Bb = B + (size_t)z * b_zs + (size_t)n0 * ldb;

  // staging: window w covers LDS rows [8w, 8w+8); lane writes 16B at base+16*lane
  // (linear dest). Source k pre-swizzled so that swizzled ds_read is conflict-free.
  const int swz = 8 * ((lane & 7) ^ (lane >> 3));   // halves
  const int fr = lane & 15, fh = lane >> 4;

  fx4_t acc[4][4];
#pragma unroll
  for (int i = 0; i < 4; ++i)
#pragma unroll
    for (int j = 0; j < 4; ++j) {
      fx4_t zv = {0.f, 0.f, 0.f, 0.f};
      acc[i][j] = zv;
    }

  for (int k0 = 0; k0 < K; k0 += 64) {
    __syncthreads();
#pragma unroll
    for (int g = 0; g < 4; ++g) {
      int w = wv * 4 + g;
      int row = w * 8 + (lane >> 3);
      gload_lds16(Ab + (size_t)row * lda + k0 + swz, &As[w * 512]);
      gload_lds16(Bb + (size_t)row * ldb + k0 + swz, &Bs[w * 512]);
    }
    asm volatile("s_waitcnt vmcnt(0)" ::: "memory");
    __syncthreads();
#pragma unroll
    for (int kc = 0; kc < 2; ++kc) {
      h8_t af[4], bf[4];
#pragma unroll
      for (int mi = 0; mi < 4; ++mi) {
        int row = wr * 64 + mi * 16 + fr;
        int kph = (kc * 32 + fh * 8) ^ ((row & 7) * 8);
        af[mi] = *(const h8_t*)&As[row * 64 + kph];
      }
#pragma unroll
      for (int ni = 0; ni < 4; ++ni) {
        int row = wc * 64 + ni * 16 + fr;
        int kph = (kc * 32 + fh * 8) ^ ((row & 7) * 8);
        bf[ni] = *(const h8_t*)&Bs[row * 64 + kph];
      }
#pragma unroll
      for (int mi = 0; mi < 4; ++mi)
#pragma unroll
        for (int ni = 0; ni < 4; ++ni)
          acc[mi][ni] = __builtin_amdgcn_mfma_f32_16x16x32_f16(
              af[mi], bf[ni], acc[mi][ni], 0, 0, 0);
    }
  }

  float* Cb = C + (size_t)z * c_zs + (size_t)(c_row0 + m0) * ldc + c_col0 + n0;
#pragma unroll
  for (int mi = 0; mi < 4; ++mi)
#pragma unroll
    for (int ni = 0; ni < 4; ++ni)
#pragma unroll
      for (int r = 0; r < 4; ++r) {
        int row = wr * 64 + mi * 16 + fh * 4 + r;
        int col = wc * 64 + ni * 16 + fr;
        Cb[(size_t)row * ldc + col] = acc[mi][ni][r];
      }
}

// ---- row softmax: S fp32 [nrows][SYY] -> P fp16 normalized ----
__global__ __launch_bounds__(256) void k_softmax(const float* __restrict__ S,
                                                 f16* __restrict__ P, long nrows) {
  int wv = threadIdx.x >> 6;
  int lane = threadIdx.x & 63;
  long R = (long)blockIdx.x * 4 + wv;
  if (R >= nrows) return;
  const float* srow = S + R * SYY;
  f16* prow = P + R * SYY;
  float v[32];
#pragma unroll
  for (int c = 0; c < 4; ++c) {
    float4 a = *(const float4*)(srow + c * 512 + lane * 8);
    float4 b = *(const float4*)(srow + c * 512 + lane * 8 + 4);
    v[c * 8 + 0] = a.x; v[c * 8 + 1] = a.y; v[c * 8 + 2] = a.z; v[c * 8 + 3] = a.w;
    v[c * 8 + 4] = b.x; v[c * 8 + 5] = b.y; v[c * 8 + 6] = b.z; v[c * 8 + 7] = b.w;
  }
  float m = v[0];
#pragma unroll
  for (int i = 1; i < 32; ++i) m = fmaxf(m, v[i]);
#pragma unroll
  for (int off = 32; off > 0; off >>= 1) m = fmaxf(m, __shfl_xor(m, off));
  float l = 0.f;
#pragma unroll
  for (int i = 0; i < 32; ++i) { v[i] = __expf(v[i] - m); l += v[i]; }
#pragma unroll
  for (int off = 32; off > 0; off >>= 1) l += __shfl_xor(l, off);
  float r = 1.0f / l;
  f16 h[32] __attribute__((aligned(16)));
#pragma unroll
  for (int i = 0; i < 32; ++i) h[i] = (f16)(v[i] * r);
#pragma unroll
  for (int c = 0; c < 4; ++c)
    *(uint4*)(prow + c * 512 + lane * 8) = *(const uint4*)&h[c * 8];
}

extern "C" void kernel_launch(void* const* d_in, const int* in_sizes, int n_in,
                              void* d_out, int out_size, void* d_ws, size_t ws_size,
                              hipStream_t stream) {
  (void)in_sizes; (void)n_in; (void)out_size;
  const float* x = (const float*)d_in[0];
  const float* y = (const float*)d_in[1];
  float* out = (float*)d_out;

  // x -> left half of out (all batches, independent of ws mode)
  k_copy_x<<<2048, 256, 0, stream>>>((const float4*)x, out,
                                     (long)NBATCH * SX * (DDIM / 4));

  // ws layout per group: S(fp32) | P16 | X16 | Y16 | Yt16
  size_t per_batch = (size_t)SX * SYY * 4 + (size_t)SX * SYY * 2 +
                     (size_t)SX * DDIM * 2 + (size_t)SYY * DDIM * 2 +
                     (size_t)DDIM * SYY * 2;
  int nb = (int)(ws_size / per_batch);
  if (nb > NBATCH) nb = NBATCH;
  int CH = SX;
  if (nb < 1) {
    nb = 1;
    size_t conv = (size_t)SX * DDIM * 2 + (size_t)SYY * DDIM * 2 +
                  (size_t)DDIM * SYY * 2;
    size_t avail = ws_size > conv ? ws_size - conv : 0;
    long ch = (long)(avail / ((size_t)SYY * 6));
    ch = (ch / 128) * 128;
    if (ch < 128) ch = 128;
    if (ch > SX) ch = SX;
    CH = (int)ch;
  }

  char* w = (char*)d_ws;
  float* Sbuf = (float*)w;
  size_t off = (size_t)nb * CH * SYY * 4;
  f16* Pbuf = (f16*)(w + off); off += (size_t)nb * CH * SYY * 2;
  f16* X16 = (f16*)(w + off);  off += (size_t)nb * SX * DDIM * 2;
  f16* Y16 = (f16*)(w + off);  off += (size_t)nb * SYY * DDIM * 2;
  f16* Yt16 = (f16*)(w + off);

  for (int b0 = 0; b0 < NBATCH; b0 += nb) {
    int nbc = (NBATCH - b0 < nb) ? (NBATCH - b0) : nb;
    k_cvt16<<<2048, 256, 0, stream>>>(
        (const float4*)(x + (size_t)b0 * SX * DDIM), (h4_t*)X16,
        (long)nbc * SX * (DDIM / 4));
    dim3 tg(DDIM / 64, SYY / 64, nbc);
    k_trans<<<tg, 256, 0, stream>>>(y + (size_t)b0 * SYY * DDIM, Y16, Yt16);

    for (int i0 = 0; i0 < SX; i0 += CH) {
      dim3 g1(SYY / 128, CH / 128, nbc);
      k_gemm<<<g1, 256, 0, stream>>>(X16, (long)SX * DDIM, i0, DDIM,
                                     Y16, (long)SYY * DDIM, DDIM,
                                     Sbuf, (long)CH * SYY, 0, SYY, 0,
                                     DDIM);
      long nrows = (long)nbc * CH;
      k_softmax<<<(unsigned)((nrows + 3) / 4), 256, 0, stream>>>(Sbuf, Pbuf, nrows);
      dim3 g2(DDIM / 128, CH / 128, nbc);
      k_gemm<<<g2, 256, 0, stream>>>(Pbuf, (long)CH * SYY, 0, SYY,
                                     Yt16, (long)DDIM * SYY, SYY,
                                     out + (size_t)b0 * SX * 2 * DDIM,
                                     (long)SX * 2 * DDIM, i0, 2 * DDIM, DDIM,
                                     SYY);
    }
  }
}

// Round 3
// 237.012 us; speedup vs baseline: 1.3934x; 1.3934x over previous
//
#include <hip/hip_runtime.h>
#include <stdint.h>

#define SX 2048
#define SYY 2048
#define DDIM 1024
#define NBATCH 8

typedef _Float16 f16;
typedef __attribute__((ext_vector_type(4))) _Float16 h4_t;
typedef __attribute__((ext_vector_type(8))) _Float16 h8_t;
typedef __attribute__((ext_vector_type(4))) float fx4_t;

__device__ __forceinline__ void gload_lds16(const void* g, void* l) {
  __builtin_amdgcn_global_load_lds((const __attribute__((address_space(1))) void*)g,
                                   (__attribute__((address_space(3))) void*)l,
                                   16, 0, 0);
}

// ---- prep: copy x into out[:, :, 0:D] (fp32) AND convert x -> fp16 ----
__global__ __launch_bounds__(256) void k_prep_x(const float4* __restrict__ x,
                                                float* __restrict__ out,
                                                h4_t* __restrict__ x16, long n4) {
  long i = (long)blockIdx.x * blockDim.x + threadIdx.x;
  long stride = (long)gridDim.x * blockDim.x;
  for (; i < n4; i += stride) {
    long bi = i >> 8;            // / (DDIM/4)
    int dq = (int)(i & 255);
    float4 v = x[i];
    *(float4*)(out + bi * (2 * DDIM) + dq * 4) = v;
    h4_t h = { (f16)v.x, (f16)v.y, (f16)v.z, (f16)v.w };
    x16[i] = h;
  }
}

// ---- y[z][j][d] fp32 -> Y16[z][j][d] fp16 and Yt16[z][d][j] fp16 ----
__global__ __launch_bounds__(256) void k_trans(const float* __restrict__ y,
                                               f16* __restrict__ y16,
                                               f16* __restrict__ yt16) {
  __shared__ f16 tile[64][72];
  int z = blockIdx.z;
  int d0 = blockIdx.x * 64, j0 = blockIdx.y * 64;
  const float* yb = y + (size_t)z * SYY * DDIM;
  f16* y16b = y16 + (size_t)z * SYY * DDIM;
  f16* ytb = yt16 + (size_t)z * DDIM * SYY;
  int t = threadIdx.x;
  int jl = t >> 2;
  int dq = t & 3;
#pragma unroll
  for (int s = 0; s < 4; ++s) {
    int dl = dq * 16 + s * 4;
    float4 v = *(const float4*)(yb + (size_t)(j0 + jl) * DDIM + d0 + dl);
    h4_t h = { (f16)v.x, (f16)v.y, (f16)v.z, (f16)v.w };
    *(h4_t*)(y16b + (size_t)(j0 + jl) * DDIM + d0 + dl) = h;
    *(h4_t*)&tile[jl][dl] = h;
  }
  __syncthreads();
  int dl2 = t >> 2;
  int jq = t & 3;
  f16 vbuf[16] __attribute__((aligned(16)));
#pragma unroll
  for (int u = 0; u < 16; ++u) vbuf[u] = tile[jq * 16 + u][dl2];
  f16* orow = ytb + (size_t)(d0 + dl2) * SYY + j0 + jq * 16;
  *(uint4*)orow = *(const uint4*)&vbuf[0];
  *(uint4*)(orow + 8) = *(const uint4*)&vbuf[8];
}

// ==== 256x256 8-phase GEMM: C[m][n] = sum_k A[m][k]*B[n][k] (both K-major) ====
// 8 waves (2M x 4N), BK=64, 8-slot LDS ring (16KB half-tiles), counted vmcnt.
// Slot row maps (per 16KB slot, LDS row l in 0..127, 64 f16 each):
//  A-lo slotX: global m = (l>>6)*128 + (l&63)        (reads: phase 0 only)
//  A-hi slotX: global m = (l>>6)*128 + 64 + (l&63)   (reads: phase 2 only)
//  B-lo slotX: global n = (l>>5)*64 + (l&31)         (reads: phase 0 only)
//  B-hi slotX: global n = (l>>5)*64 + 32 + (l&31)    (reads: phase 1 only)
// k-blocks XOR-swizzled: LDS[l][b] holds global k-block b ^ (l&7).
#define PH_BAR() __builtin_amdgcn_s_barrier()
#define WAIT_LGKM() asm volatile("s_waitcnt lgkmcnt(0)" ::: "memory")

#define STAGE_A(SLOT, HALF, T) {                                               \
    const f16* s_ = aRow + (size_t)((HALF) * 64) * lda + (T) * 64;             \
    f16* d_ = lds + (SLOT) * 8192 + dstoff;                                    \
    gload_lds16(s_, d_);                                                       \
    gload_lds16(s_ + (size_t)128 * lda, d_ + 4096); }

#define STAGE_B(SLOT, HALF, T) {                                               \
    const f16* s_ = bRow + (size_t)((HALF) * 32) * ldb + (T) * 64;             \
    f16* d_ = lds + (SLOT) * 8192 + dstoff;                                    \
    gload_lds16(s_, d_);                                                       \
    gload_lds16(s_ + (size_t)128 * ldb, d_ + 4096); }

#define RD_A(PTR, CB) { _Pragma("unroll") for (int i_ = 0; i_ < 4; ++i_) {     \
    af[i_][0] = *(const h8_t*)((PTR) + (CB) + i_ * 2048 + kb0);                \
    af[i_][1] = *(const h8_t*)((PTR) + (CB) + i_ * 2048 + kb1); } }

#define RD_B(PTR, CB, NH) { _Pragma("unroll") for (int j_ = 0; j_ < 2; ++j_) { \
    bf[(NH) + j_][0] = *(const h8_t*)((PTR) + (CB) + j_ * 2048 + kb0);         \
    bf[(NH) + j_][1] = *(const h8_t*)((PTR) + (CB) + j_ * 2048 + kb1); } }

#define MM(MH, NH) { __builtin_amdgcn_s_setprio(1);                            \
  _Pragma("unroll") for (int i_ = 0; i_ < 4; ++i_)                             \
  _Pragma("unroll") for (int j_ = 0; j_ < 2; ++j_) {                           \
    acc[(MH) + i_][(NH) + j_] = __builtin_amdgcn_mfma_f32_16x16x32_f16(        \
        af[i_][0], bf[(NH) + j_][0], acc[(MH) + i_][(NH) + j_], 0, 0, 0);      \
    acc[(MH) + i_][(NH) + j_] = __builtin_amdgcn_mfma_f32_16x16x32_f16(        \
        af[i_][1], bf[(NH) + j_][1], acc[(MH) + i_][(NH) + j_], 0, 0, 0); }    \
  __builtin_amdgcn_s_setprio(0); }

__global__ __launch_bounds__(512, 2) void k_gemm8(
    const f16* __restrict__ A, long a_zs, int a_row0, int lda,
    const f16* __restrict__ B, long b_zs, int ldb,
    float* __restrict__ C, long c_zs, int c_row0, int ldc, int c_col0,
    int K, int ntm, int ntn, int nblk)
{
  __shared__ f16 lds[65536];   // 128 KiB: 8 slots x 16 KB

  int bid = blockIdx.x;
  int id = bid;
  if ((nblk & 7) == 0) {               // bijective XCD swizzle
    int cpx = nblk >> 3;
    id = (bid & 7) * cpx + (bid >> 3);
  }
  int tpz = ntm * ntn;
  int z = id / tpz;
  int rem = id - z * tpz;
  int mt = rem / ntn;
  int ntl = rem - mt * ntn;
  int m0 = mt * 256, n0 = ntl * 256;

  const int tid = threadIdx.x;
  const int lane = tid & 63, w = tid >> 6;
  const int wr = w >> 2, wc = w & 3;
  const int fr = lane & 15, fh = lane >> 4;

  const f16* Ab = A + (size_t)z * a_zs + (size_t)(a_row0 + m0) * lda;
  const f16* Bb = B + (size_t)z * b_zs + (size_t)n0 * ldb;

  // staging: linear LDS dest (wave-uniform base + lane*16B); per-thread source
  // row permuted to match slot maps; source k pre-swizzled for XOR ds_read.
  const int l0 = 8 * w + (lane >> 3);              // LDS row written (first op)
  const int r0a = l0;                              // A-lo: row l0 (+HALF*64)
  const int r0b = ((l0 >> 5) << 6) | (l0 & 31);    // B-lo: (l>>5)*64+(l&31)
  const int swz = 8 * ((lane & 7) ^ (lane >> 3));
  const f16* aRow = Ab + (size_t)r0a * lda + swz;
  const f16* bRow = Bb + (size_t)r0b * ldb + swz;
  const int dstoff = w * 512 + lane * 8;           // f16 units within a slot

  const char* ldsAlo = (const char*)lds + wr * 8192 + fr * 128;        // slot0
  const char* ldsAhi = ldsAlo + 16384;                                 // slot1
  const char* ldsBlo = (const char*)lds + 32768 + wc * 4096 + fr * 128;// slot2
  const char* ldsBhi = ldsBlo + 16384;                                 // slot3
  const int kb0 = ((0 + fh) ^ (fr & 7)) * 16;
  const int kb1 = ((4 + fh) ^ (fr & 7)) * 16;

  const int nt = K >> 6;       // K-tiles (even, >= 2)
  const int ng = nt >> 1;

  fx4_t acc[8][4];
#pragma unroll
  for (int i = 0; i < 8; ++i)
#pragma unroll
    for (int j = 0; j < 4; ++j) {
      fx4_t zv = {0.f, 0.f, 0.f, 0.f};
      acc[i][j] = zv;
    }
  h8_t af[4][2], bf[4][2];

  // prologue: tile0 -> slots 0,1,2,3 ; tile1 -> slots 4,6,7 (slot5 at phase 0)
  STAGE_A(0, 0, 0); STAGE_A(1, 1, 0); STAGE_B(2, 0, 0); STAGE_B(3, 1, 0);
  STAGE_A(4, 0, 1); STAGE_B(6, 0, 1); STAGE_B(7, 1, 1);
  asm volatile("s_waitcnt vmcnt(6)" ::: "memory");   // tile0 landed
  PH_BAR();

  for (int g = 0; g < ng; ++g) {
    const int T1 = 2 * g + 1, T2 = 2 * g + 2, T3 = 2 * g + 3;
    const bool nl = (g < ng - 1);
    // phase 0: read slot0(A-lo)+slot2(B-lo); stage slot5 <- A-hi(T1)
    RD_A(ldsAlo, 0); RD_B(ldsBlo, 0, 0);
    STAGE_A(5, 1, T1);
    PH_BAR(); WAIT_LGKM();
    MM(0, 0);
    PH_BAR();
    // phase 1: read slot3(B-hi); stage slot0 <- A-lo(T2)
    RD_B(ldsBhi, 0, 2);
    if (nl) STAGE_A(0, 0, T2);
    PH_BAR(); WAIT_LGKM();
    MM(0, 2);
    PH_BAR();
    // phase 2: read slot1(A-hi); stage slot2 <- B-lo(T2)
    RD_A(ldsAhi, 0);
    if (nl) STAGE_B(2, 0, T2);
    PH_BAR(); WAIT_LGKM();
    MM(4, 0);
    PH_BAR();
    // phase 3: no reads; stage slot3 <- B-hi(T2); checkpoint
    if (nl) STAGE_B(3, 1, T2);
    PH_BAR(); WAIT_LGKM();
    MM(4, 2);
    if (nl) { asm volatile("s_waitcnt vmcnt(6)" ::: "memory"); }
    else    { asm volatile("s_waitcnt vmcnt(0)" ::: "memory"); }
    PH_BAR();
    // phase 4: read slot4(A-lo)+slot6(B-lo) of buf1; stage slot1 <- A-hi(T2)
    RD_A(ldsAlo, 65536); RD_B(ldsBlo, 65536, 0);
    if (nl) STAGE_A(1, 1, T2);
    PH_BAR(); WAIT_LGKM();
    MM(0, 0);
    PH_BAR();
    // phase 5: read slot7(B-hi); stage slot4 <- A-lo(T3)
    RD_B(ldsBhi, 65536, 2);
    if (nl) STAGE_A(4, 0, T3);
    PH_BAR(); WAIT_LGKM();
    MM(0, 2);
    PH_BAR();
    // phase 6: read slot5(A-hi); stage slot6 <- B-lo(T3)
    RD_A(ldsAhi, 65536);
    if (nl) STAGE_B(6, 0, T3);
    PH_BAR(); WAIT_LGKM();
    MM(4, 0);
    PH_BAR();
    // phase 7: stage slot7 <- B-hi(T3); checkpoint
    if (nl) STAGE_B(7, 1, T3);
    PH_BAR(); WAIT_LGKM();
    MM(4, 2);
    asm volatile("s_waitcnt vmcnt(6)" ::: "memory");
    PH_BAR();
  }

  float* Cb = C + (size_t)z * c_zs +
              (size_t)(c_row0 + m0 + wr * 128) * ldc + c_col0 + n0 + wc * 64;
#pragma unroll
  for (int mi = 0; mi < 8; ++mi)
#pragma unroll
    for (int ni = 0; ni < 4; ++ni)
#pragma unroll
      for (int r = 0; r < 4; ++r)
        Cb[(size_t)(mi * 16 + fh * 4 + r) * ldc + ni * 16 + fr] = acc[mi][ni][r];
}

// ---- row softmax: S fp32 [nrows][SYY] -> P fp16 normalized ----
__global__ __launch_bounds__(256) void k_softmax(const float* __restrict__ S,
                                                 f16* __restrict__ P, long nrows) {
  int wv = threadIdx.x >> 6;
  int lane = threadIdx.x & 63;
  long R = (long)blockIdx.x * 4 + wv;
  if (R >= nrows) return;
  const float* srow = S + R * SYY;
  f16* prow = P + R * SYY;
  float v[32];
#pragma unroll
  for (int c = 0; c < 4; ++c) {
    float4 a = *(const float4*)(srow + c * 512 + lane * 8);
    float4 b = *(const float4*)(srow + c * 512 + lane * 8 + 4);
    v[c * 8 + 0] = a.x; v[c * 8 + 1] = a.y; v[c * 8 + 2] = a.z; v[c * 8 + 3] = a.w;
    v[c * 8 + 4] = b.x; v[c * 8 + 5] = b.y; v[c * 8 + 6] = b.z; v[c * 8 + 7] = b.w;
  }
  float m = v[0];
#pragma unroll
  for (int i = 1; i < 32; ++i) m = fmaxf(m, v[i]);
#pragma unroll
  for (int off = 32; off > 0; off >>= 1) m = fmaxf(m, __shfl_xor(m, off));
  float l = 0.f;
#pragma unroll
  for (int i = 0; i < 32; ++i) { v[i] = __expf(v[i] - m); l += v[i]; }
#pragma unroll
  for (int off = 32; off > 0; off >>= 1) l += __shfl_xor(l, off);
  float r = 1.0f / l;
  f16 h[32] __attribute__((aligned(16)));
#pragma unroll
  for (int i = 0; i < 32; ++i) h[i] = (f16)(v[i] * r);
#pragma unroll
  for (int c = 0; c < 4; ++c)
    *(uint4*)(prow + c * 512 + lane * 8) = *(const uint4*)&h[c * 8];
}

extern "C" void kernel_launch(void* const* d_in, const int* in_sizes, int n_in,
                              void* d_out, int out_size, void* d_ws, size_t ws_size,
                              hipStream_t stream) {
  (void)in_sizes; (void)n_in; (void)out_size;
  const float* x = (const float*)d_in[0];
  const float* y = (const float*)d_in[1];
  float* out = (float*)d_out;

  // ws layout per group: S(fp32) | P16 | X16 | Y16 | Yt16
  size_t per_batch = (size_t)SX * SYY * 4 + (size_t)SX * SYY * 2 +
                     (size_t)SX * DDIM * 2 + (size_t)SYY * DDIM * 2 +
                     (size_t)DDIM * SYY * 2;
  int nb = (int)(ws_size / per_batch);
  if (nb > NBATCH) nb = NBATCH;
  int CH = SX;
  if (nb < 1) {
    nb = 1;
    size_t conv = (size_t)SX * DDIM * 2 + (size_t)SYY * DDIM * 2 +
                  (size_t)DDIM * SYY * 2;
    size_t avail = ws_size > conv ? ws_size - conv : 0;
    long ch = (long)(avail / ((size_t)SYY * 6));
    ch = (ch / 256) * 256;
    if (ch < 256) ch = 256;
    if (ch > SX) ch = SX;
    CH = (int)ch;
  }

  char* w = (char*)d_ws;
  float* Sbuf = (float*)w;
  size_t off = (size_t)nb * CH * SYY * 4;
  f16* Pbuf = (f16*)(w + off); off += (size_t)nb * CH * SYY * 2;
  f16* X16 = (f16*)(w + off);  off += (size_t)nb * SX * DDIM * 2;
  f16* Y16 = (f16*)(w + off);  off += (size_t)nb * SYY * DDIM * 2;
  f16* Yt16 = (f16*)(w + off);

  for (int b0 = 0; b0 < NBATCH; b0 += nb) {
    int nbc = (NBATCH - b0 < nb) ? (NBATCH - b0) : nb;
    k_prep_x<<<2048, 256, 0, stream>>>(
        (const float4*)(x + (size_t)b0 * SX * DDIM),
        out + (size_t)b0 * SX * 2 * DDIM, (h4_t*)X16,
        (long)nbc * SX * (DDIM / 4));
    dim3 tg(DDIM / 64, SYY / 64, nbc);
    k_trans<<<tg, 256, 0, stream>>>(y + (size_t)b0 * SYY * DDIM, Y16, Yt16);

    for (int i0 = 0; i0 < SX; i0 += CH) {
      int ntm = CH / 256;
      int nblk1 = nbc * ntm * (SYY / 256);
      k_gemm8<<<nblk1, 512, 0, stream>>>(X16, (long)SX * DDIM, i0, DDIM,
                                         Y16, (long)SYY * DDIM, DDIM,
                                         Sbuf, (long)CH * SYY, 0, SYY, 0,
                                         DDIM, ntm, SYY / 256, nblk1);
      long nrows = (long)nbc * CH;
      k_softmax<<<(unsigned)((nrows + 3) / 4), 256, 0, stream>>>(Sbuf, Pbuf, nrows);
      int nblk2 = nbc * ntm * (DDIM / 256);
      k_gemm8<<<nblk2, 512, 0, stream>>>(Pbuf, (long)CH * SYY, 0, SYY,
                                         Yt16, (long)DDIM * SYY, SYY,
                                         out + (size_t)b0 * SX * 2 * DDIM,
                                         (long)SX * 2 * DDIM, i0, 2 * DDIM, DDIM,
                                         SYY, ntm, DDIM / 256, nblk2);
    }
  }
}